// Round 9
// baseline (369.957 us; speedup 1.0000x reference)
//
#include <hip/hip_runtime.h>
#include <hip/hip_bf16.h>

typedef __attribute__((ext_vector_type(8))) short short8;
typedef __attribute__((ext_vector_type(4))) float f32x4;

static constexpr int NN = 64;
static constexpr int C  = 128;
static constexpr int H  = 56;
static constexpr int W  = 56;
static constexpr int HP = 58;          // padded spatial extent
static constexpr int ROWB = HP * 256;  // padded row stride in bytes (NHWC bf16)
static constexpr int XSLOT = 15360;    // LDS bytes per X row slot (15 x 1KB)

__device__ __forceinline__ void gload16(const void* g, void* l) {
    __builtin_amdgcn_global_load_lds(
        (const __attribute__((address_space(1))) unsigned int*)g,
        (__attribute__((address_space(3))) unsigned int*)l, 16, 0, 0);
}

__device__ __forceinline__ f32x4 mfma16(short8 a, short8 b, f32x4 c) {
    return __builtin_amdgcn_mfma_f32_16x16x32_bf16(a, b, c, 0, 0, 0);
}

// ---------------------------------------------------------------------------
// Pack weights into 16x16x32 MFMA B-fragment order.
// Fragment f = (tap*4 + ks)*8 + ob   (ks = c>>5, ob = o>>4), 1 KB each.
// Within fragment: lane = (o&15) | (((c>>3)&3)<<4), byte j = c&7:
//   lane l holds W[o = ob*16 + (l&15)][c = ks*32 + (l>>4)*8 + j]  (x scale[o])
// This is exactly the B-frag mapping verified by R1's passing kernel.
// ---------------------------------------------------------------------------
__global__ __launch_bounds__(128)
void pack_weights(const float* __restrict__ w, const float* __restrict__ g,
                  const float* __restrict__ b, const float* __restrict__ m,
                  const float* __restrict__ v, __hip_bfloat16* __restrict__ Wp,
                  float* __restrict__ shift)
{
    int o = blockIdx.x;
    int c = threadIdx.x;
    float scale = g[o] * rsqrtf(v[o] + 1e-5f);
    if (c == 0) shift[o] = b[o] - m[o] * scale;
    const float* ws = w + ((size_t)o * C + c) * 9;
    int ks = c >> 5, lane = (o & 15) | (((c >> 3) & 3) << 4), jj = c & 7;
    int ob = o >> 4;
    #pragma unroll
    for (int tap = 0; tap < 9; ++tap) {
        size_t f = (size_t)(tap * 4 + ks) * 8 + ob;
        Wp[f * 512 + lane * 8 + jj] = __float2bfloat16(ws[tap] * scale);
    }
}

// ---------------------------------------------------------------------------
// NCHW fp32 -> padded NHWC bf16 (interior only; halo zeroed separately).
// ---------------------------------------------------------------------------
__global__ __launch_bounds__(256)
void transform_x(const float* __restrict__ x, __hip_bfloat16* __restrict__ Xp)
{
    __shared__ float t[C * 57];
    int bid = blockIdx.x;
    int n = bid / H, h = bid % H;
    int tid = threadIdx.x;

    #pragma unroll
    for (int i = 0; i < 7; ++i) {
        int idx4 = i * 256 + tid;
        int c  = idx4 / 14;
        int wq = (idx4 % 14) * 4;
        const float* p = x + ((size_t)(n * C + c)) * (H * W) + h * W + wq;
        float4 vv = *(const float4*)p;
        t[c * 57 + wq + 0] = vv.x;
        t[c * 57 + wq + 1] = vv.y;
        t[c * 57 + wq + 2] = vv.z;
        t[c * 57 + wq + 3] = vv.w;
    }
    __syncthreads();
    #pragma unroll
    for (int i = 0; i < 28; ++i) {
        int idx = i * 256 + tid;
        int c = idx & 127, w = idx >> 7;
        float vv = t[c * 57 + w];
        Xp[(((size_t)n * HP + (h + 1)) * HP + (w + 1)) * C + c] = __float2bfloat16(vv);
    }
}

// ---------------------------------------------------------------------------
// Zero only the halo of a padded NHWC buffer.
// ---------------------------------------------------------------------------
__global__ __launch_bounds__(256)
void zero_halo(__hip_bfloat16* __restrict__ buf)
{
    int idx = blockIdx.x * 256 + threadIdx.x;
    int n = idx / (228 * 16);
    int rem = idx % (228 * 16);
    int p = rem >> 4, l = rem & 15;
    int y, xq;
    if (p < 58)       { y = 0;  xq = p; }
    else if (p < 116) { y = 57; xq = p - 58; }
    else { int q = p - 116; y = 1 + (q >> 1); xq = (q & 1) * 57; }
    short8* dst = (short8*)(buf + (((size_t)n * HP + y) * HP + xq) * C + l * 8);
    *dst = short8{0,0,0,0,0,0,0,0};
}

// ---------------------------------------------------------------------------
// Implicit-GEMM 3x3 conv, occupancy-first with SMALL per-wave footprint.
// Block = 512 thr (8 waves), 2 output rows x O=128.
// Wave (wm = wave>>2, mh = (wave>>1)&1, oh = wave&1):
//   output row h0+wm, m in [mh*32,+32), o in [oh*64,+64)
//   -> acc[2][4] f32x4 = 32 regs (16x16x32 MFMA, mapping verified in R1).
// X: 3-slot LDS ring, 15,360 B/slot (47 KB total -> 3 blocks/CU = 24 waves);
//    XOR swizzle ((pos&15)<<4) via pre-swizzled gload_lds source.
//    Ring: prologue rows q0..q2 -> slots 0..2; q3 -> slot 0 after kh=0.
//    sbase = ((kh+wm)%3): wm=1/kh=2 reads slot 0 = q3.  3 barriers total.
// W: register-direct 16B coalesced loads from fragment-ordered Wp
//    (L1-shared across 24 waves; no W-LDS, no W barriers).
// WHICH==0: D[m][o] -> relu(D+shift) -> NHWC bf16 padded (Y1)
// WHICH==1: D[o][m] -> relu(D+shift+identity) -> NCHW fp32
// ---------------------------------------------------------------------------
template<int WHICH>
__global__ __launch_bounds__(512, 6)
void conv3x3_kernel(const __hip_bfloat16* __restrict__ Xp,
                    const __hip_bfloat16* __restrict__ Wp,
                    const float* __restrict__ shift,
                    const float* __restrict__ ident,
                    void* __restrict__ outp)
{
    __shared__ char s_x[3 * XSLOT + 2048];   // 3 ring slots + read-overhang pad

    const int tid  = threadIdx.x;
    const int wave = tid >> 6;       // 0..7
    const int lane = tid & 63;
    const int lr   = lane & 15;
    const int lg   = lane >> 4;      // 0..3
    const int wm   = wave >> 2;      // output row (0..1)
    const int mh   = (wave >> 1) & 1;// m-half (0..1)
    const int oh   = wave & 1;       // o-half (0..1)

    const int bid0 = blockIdx.x;
    const int bid  = (bid0 & 7) * 224 + (bid0 >> 3);   // XCD swizzle (1792=8*224)
    const int n = bid / 28, h0 = (bid % 28) * 2;

    const char* xbase = (const char*)Xp + ((size_t)n * HP + h0) * ROWB;

    // prologue: stage padded rows q0..q2 -> slots 0..2 (45 x 1KB units)
    #pragma unroll
    for (int i = 0; i < 6; ++i) {
        int u = wave + i * 8;
        if (u < 45) {
            int q = u / 15, blk = u % 15;
            int d = blk * 1024 + lane * 16;
            int s = d ^ (((d >> 8) & 15) << 4);
            gload16(xbase + (size_t)q * ROWB + s, s_x + q * XSLOT + d);
        }
    }

    // per-lane W fragment base (bf16 elements)
    const __hip_bfloat16* wlane = Wp + lane * 8;

    f32x4 acc[2][4];
    #pragma unroll
    for (int i = 0; i < 2; ++i)
        #pragma unroll
        for (int j = 0; j < 4; ++j)
            acc[i][j] = f32x4{0.f, 0.f, 0.f, 0.f};

#define KHBLOCK(KH)                                                           \
    {                                                                         \
        const int sbase = (((KH) + wm) % 3) * XSLOT;                          \
        _Pragma("unroll")                                                     \
        for (int kwi = 0; kwi < 3; ++kwi) {                                   \
            const int tap = (KH) * 3 + kwi;                                   \
            _Pragma("unroll")                                                 \
            for (int ks = 0; ks < 4; ++ks) {                                  \
                const int cb = ks * 64 + lg * 16;                             \
                short8 wb[4];                                                 \
                _Pragma("unroll")                                             \
                for (int of = 0; of < 4; ++of)                                \
                    wb[of] = *(const short8*)(wlane +                         \
                        (size_t)((tap * 4 + ks) * 8 + oh * 4 + of) * 512);    \
                short8 xa[2];                                                 \
                _Pragma("unroll")                                             \
                for (int mf = 0; mf < 2; ++mf) {                              \
                    int row = mh * 32 + mf * 16 + lr + kwi;                   \
                    int off = (row * 256 + cb) ^ ((row & 15) << 4);           \
                    xa[mf] = *(const short8*)(s_x + sbase + off);             \
                }                                                             \
                _Pragma("unroll")                                             \
                for (int mf = 0; mf < 2; ++mf)                                \
                    _Pragma("unroll")                                         \
                    for (int of = 0; of < 4; ++of) {                          \
                        if (WHICH == 0)                                       \
                            acc[mf][of] = mfma16(xa[mf], wb[of], acc[mf][of]);\
                        else                                                  \
                            acc[mf][of] = mfma16(wb[of], xa[mf], acc[mf][of]);\
                    }                                                         \
            }                                                                 \
        }                                                                     \
    }

    __syncthreads();                     // rows q0..q2 staged
    KHBLOCK(0)
    __syncthreads();                     // slot 0 (q0) reads done
    // async prefetch padded row q3 -> slot 0 (read only at kh=2 by wm=1;
    // drained by the compiler vmcnt(0) at the next barrier)
    #pragma unroll
    for (int i = 0; i < 2; ++i) {
        int u = wave + i * 8;
        if (u < 15) {
            int d = u * 1024 + lane * 16;
            int s = d ^ (((d >> 8) & 15) << 4);
            gload16(xbase + (size_t)3 * ROWB + s, s_x + d);
        }
    }
    KHBLOCK(1)
    __syncthreads();                     // q3 staged
    KHBLOCK(2)
#undef KHBLOCK

    // 16x16 C/D layout (verified R1): col = lane&15, row = (lane>>4)*4 + r
    if (WHICH == 0) {
        // D[m][o]: m = mh*32 + mf*16 + lg*4 + r, o = oh*64 + of*16 + lr
        __hip_bfloat16* o1 = (__hip_bfloat16*)outp;
        size_t rowb = ((size_t)n * HP + (h0 + wm + 1)) * HP;
        #pragma unroll
        for (int of = 0; of < 4; ++of) {
            int o = oh * 64 + of * 16 + lr;
            float sh = shift[o];
            #pragma unroll
            for (int mf = 0; mf < 2; ++mf) {
                #pragma unroll
                for (int r = 0; r < 4; ++r) {
                    int m = mh * 32 + mf * 16 + lg * 4 + r;
                    if (m < W) {
                        float f = acc[mf][of][r] + sh;
                        f = f > 0.f ? f : 0.f;
                        o1[(rowb + m + 1) * C + o] = __float2bfloat16(f);
                    }
                }
            }
        }
    } else {
        // D[o][m]: o = oh*64 + of*16 + lg*4 + r, m = mh*32 + mf*16 + lr
        float* o2 = (float*)outp;
        int h = h0 + wm;
        #pragma unroll
        for (int mf = 0; mf < 2; ++mf) {
            int m = mh * 32 + mf * 16 + lr;
            if (m < W) {
                #pragma unroll
                for (int of = 0; of < 4; ++of) {
                    int ob = oh * 64 + of * 16 + lg * 4;
                    f32x4 sh = *(const f32x4*)(shift + ob);
                    #pragma unroll
                    for (int r = 0; r < 4; ++r) {
                        int o = ob + r;
                        size_t idx = ((size_t)(n * C + o) * H + h) * W + m;
                        float f = acc[mf][of][r] + sh[r] + ident[idx];
                        o2[idx] = f > 0.f ? f : 0.f;
                    }
                }
            }
        }
    }
}

// ---------------------------------------------------------------------------
extern "C" void kernel_launch(void* const* d_in, const int* in_sizes, int n_in,
                              void* d_out, int out_size, void* d_ws, size_t ws_size,
                              hipStream_t stream)
{
    const float* x  = (const float*)d_in[0];
    const float* w1 = (const float*)d_in[1];
    const float* g1 = (const float*)d_in[2];
    const float* b1 = (const float*)d_in[3];
    const float* m1 = (const float*)d_in[4];
    const float* v1 = (const float*)d_in[5];
    const float* w2 = (const float*)d_in[6];
    const float* g2 = (const float*)d_in[7];
    const float* b2 = (const float*)d_in[8];
    const float* m2 = (const float*)d_in[9];
    const float* v2 = (const float*)d_in[10];
    float* out = (float*)d_out;

    char* ws = (char*)d_ws;
    const size_t PADBUF = (size_t)NN * HP * HP * C * 2;    // 55,107,584 B
    const size_t WBUF   = (size_t)288 * 1024;              // 294,912 B
    size_t oX  = 0;
    size_t oY  = oX + PADBUF + 32768;    // slack for staging over-read
    size_t oW1 = oY + PADBUF + 32768;
    size_t oW2 = oW1 + WBUF;
    size_t oS1 = oW2 + WBUF;
    size_t oS2 = oS1 + 512;

    __hip_bfloat16* Xp  = (__hip_bfloat16*)(ws + oX);
    __hip_bfloat16* Y1  = (__hip_bfloat16*)(ws + oY);
    __hip_bfloat16* W1p = (__hip_bfloat16*)(ws + oW1);
    __hip_bfloat16* W2p = (__hip_bfloat16*)(ws + oW2);
    float* s1 = (float*)(ws + oS1);
    float* s2 = (float*)(ws + oS2);

    zero_halo<<<912, 256, 0, stream>>>(Xp);
    zero_halo<<<912, 256, 0, stream>>>(Y1);

    pack_weights<<<128, 128, 0, stream>>>(w1, g1, b1, m1, v1, W1p, s1);
    pack_weights<<<128, 128, 0, stream>>>(w2, g2, b2, m2, v2, W2p, s2);
    transform_x<<<NN * H, 256, 0, stream>>>(x, Xp);

    conv3x3_kernel<0><<<NN * 28, 512, 0, stream>>>(Xp, W1p, s1, nullptr, (void*)Y1);
    conv3x3_kernel<1><<<NN * 28, 512, 0, stream>>>(Y1, W2p, s2, x, (void*)out);
}

// Round 10
// 242.447 us; speedup vs baseline: 1.5259x; 1.5259x over previous
//
#include <hip/hip_runtime.h>
#include <hip/hip_bf16.h>

typedef __attribute__((ext_vector_type(8))) short short8;
typedef __attribute__((ext_vector_type(4))) float f32x4;

static constexpr int NN = 64;
static constexpr int C  = 128;
static constexpr int H  = 56;
static constexpr int W  = 56;
static constexpr int HP = 58;          // padded spatial extent
static constexpr int ROWB = HP * 256;  // padded row stride in bytes (NHWC bf16)
static constexpr int XSLOT = 15360;    // LDS bytes per X row slot (15 x 1KB)

__device__ __forceinline__ void gload16(const void* g, void* l) {
    __builtin_amdgcn_global_load_lds(
        (const __attribute__((address_space(1))) unsigned int*)g,
        (__attribute__((address_space(3))) unsigned int*)l, 16, 0, 0);
}

__device__ __forceinline__ f32x4 mfma16(short8 a, short8 b, f32x4 c) {
    return __builtin_amdgcn_mfma_f32_16x16x32_bf16(a, b, c, 0, 0, 0);
}

// ---------------------------------------------------------------------------
// Pack weights into 16x16x32 MFMA B-fragment order (verified R9).
// Fragment f = (tap*4 + ks)*8 + ob   (ks = c>>5, ob = o>>4), 1024 B each.
// lane l of frag holds W[o = ob*16 + (l&15)][c = ks*32 + (l>>4)*8 + j] * scale.
// One K-step s = tap*4+ks is a contiguous 8 KB run (8 ob frags) -> LDS tile.
// ---------------------------------------------------------------------------
__global__ __launch_bounds__(128)
void pack_weights(const float* __restrict__ w, const float* __restrict__ g,
                  const float* __restrict__ b, const float* __restrict__ m,
                  const float* __restrict__ v, __hip_bfloat16* __restrict__ Wp,
                  float* __restrict__ shift)
{
    int o = blockIdx.x;
    int c = threadIdx.x;
    float scale = g[o] * rsqrtf(v[o] + 1e-5f);
    if (c == 0) shift[o] = b[o] - m[o] * scale;
    const float* ws = w + ((size_t)o * C + c) * 9;
    int ks = c >> 5, lane = (o & 15) | (((c >> 3) & 3) << 4), jj = c & 7;
    int ob = o >> 4;
    #pragma unroll
    for (int tap = 0; tap < 9; ++tap) {
        size_t f = (size_t)(tap * 4 + ks) * 8 + ob;
        Wp[f * 512 + lane * 8 + jj] = __float2bfloat16(ws[tap] * scale);
    }
}

// ---------------------------------------------------------------------------
// NCHW fp32 -> padded NHWC bf16 (interior only; halo zeroed separately).
// ---------------------------------------------------------------------------
__global__ __launch_bounds__(256)
void transform_x(const float* __restrict__ x, __hip_bfloat16* __restrict__ Xp)
{
    __shared__ float t[C * 57];
    int bid = blockIdx.x;
    int n = bid / H, h = bid % H;
    int tid = threadIdx.x;

    #pragma unroll
    for (int i = 0; i < 7; ++i) {
        int idx4 = i * 256 + tid;
        int c  = idx4 / 14;
        int wq = (idx4 % 14) * 4;
        const float* p = x + ((size_t)(n * C + c)) * (H * W) + h * W + wq;
        float4 vv = *(const float4*)p;
        t[c * 57 + wq + 0] = vv.x;
        t[c * 57 + wq + 1] = vv.y;
        t[c * 57 + wq + 2] = vv.z;
        t[c * 57 + wq + 3] = vv.w;
    }
    __syncthreads();
    #pragma unroll
    for (int i = 0; i < 28; ++i) {
        int idx = i * 256 + tid;
        int c = idx & 127, w = idx >> 7;
        float vv = t[c * 57 + w];
        Xp[(((size_t)n * HP + (h + 1)) * HP + (w + 1)) * C + c] = __float2bfloat16(vv);
    }
}

// ---------------------------------------------------------------------------
// Zero only the halo of a padded NHWC buffer.
// ---------------------------------------------------------------------------
__global__ __launch_bounds__(256)
void zero_halo(__hip_bfloat16* __restrict__ buf)
{
    int idx = blockIdx.x * 256 + threadIdx.x;
    int n = idx / (228 * 16);
    int rem = idx % (228 * 16);
    int p = rem >> 4, l = rem & 15;
    int y, xq;
    if (p < 58)       { y = 0;  xq = p; }
    else if (p < 116) { y = 57; xq = p - 58; }
    else { int q = p - 116; y = 1 + (q >> 1); xq = (q & 1) * 57; }
    short8* dst = (short8*)(buf + (((size_t)n * HP + y) * HP + xq) * C + l * 8);
    *dst = short8{0,0,0,0,0,0,0,0};
}

// ---------------------------------------------------------------------------
// Implicit-GEMM 3x3 conv.  Block = 512 thr (8 waves), 2 output rows x O=128.
// Wave (wm = wave>>2, mh = (wave>>1)&1, oh = wave&1): row h0+wm,
// m in [mh*32,+32), o in [oh*64,+64) -> acc[2][4] f32x4 = 32 regs (R9 math).
// X: 3-slot LDS ring, XOR swizzle ((pos&15)<<4) via pre-swizzled gload_lds
//    source (verified R1-R9); q3 prefetched at step 12, consumed from step 24.
// W: LDS double-buffer of 8 KB K-step tiles (one ks-slice of one tap),
//    fragment-linear layout -> wb reads are lane-linear b128, conflict-free.
//    T3-minimum loop, ONE barrier per K-step (structure verified R7):
//      { stage(s+1 -> buf^1); compute(s from buf); sync; }
//    Stage = 1 gload16/thread; drains at the end-of-body barrier.
// Weight L2 traffic: 288 KB/block (4x less than R4/R9's per-wave streams).
// NO launch_bounds reg cap (R8/R9 lesson: caps -> scratch spill).
// WHICH==0: D[m][o] -> relu(D+shift) -> NHWC bf16 padded (Y1)
// WHICH==1: D[o][m] -> relu(D+shift+identity) -> NCHW fp32
// ---------------------------------------------------------------------------
template<int WHICH>
__global__ __launch_bounds__(512, 2)
void conv3x3_kernel(const __hip_bfloat16* __restrict__ Xp,
                    const __hip_bfloat16* __restrict__ Wp,
                    const float* __restrict__ shift,
                    const float* __restrict__ ident,
                    void* __restrict__ outp)
{
    __shared__ char s_x[3 * XSLOT + 2048];   // 46 KB ring + read-overhang pad
    __shared__ char s_w[2][8192];            // W double buffer (one K-step)

    const int tid  = threadIdx.x;
    const int wave = tid >> 6;       // 0..7
    const int lane = tid & 63;
    const int lr   = lane & 15;
    const int lg   = lane >> 4;      // 0..3
    const int wm   = wave >> 2;      // output row (0..1)
    const int mh   = (wave >> 1) & 1;// m-half (0..1)
    const int oh   = wave & 1;       // o-half (0..1)

    const int bid0 = blockIdx.x;
    const int bid  = (bid0 & 7) * 224 + (bid0 >> 3);   // XCD swizzle (1792=8*224)
    const int n = bid / 28, h0 = (bid % 28) * 2;

    const char* xbase = (const char*)Xp + ((size_t)n * HP + h0) * ROWB;
    const char* wbase = (const char*)Wp;

    // prologue: stage padded rows q0..q2 -> slots 0..2 (45 x 1KB units)
    #pragma unroll
    for (int i = 0; i < 6; ++i) {
        int u = wave + i * 8;
        if (u < 45) {
            int q = u / 15, blk = u % 15;
            int d = blk * 1024 + lane * 16;
            int s = d ^ (((d >> 8) & 15) << 4);
            gload16(xbase + (size_t)q * ROWB + s, s_x + q * XSLOT + d);
        }
    }
    // stage W K-step 0 -> s_w[0] (8 KB = 1 x 16B per thread)
    gload16(wbase + tid * 16, s_w[0] + tid * 16);

    f32x4 acc[2][4];
    #pragma unroll
    for (int i = 0; i < 2; ++i)
        #pragma unroll
        for (int j = 0; j < 4; ++j)
            acc[i][j] = f32x4{0.f, 0.f, 0.f, 0.f};

    __syncthreads();                 // X q0..q2 + W step 0 staged

    #pragma unroll
    for (int s = 0; s < 36; ++s) {
        // issue next W tile into the other buffer (drains at end-of-body sync)
        if (s < 35)
            gload16(wbase + (size_t)(s + 1) * 8192 + tid * 16,
                    s_w[(s + 1) & 1] + tid * 16);
        if (s == 12) {
            // prefetch padded row q3 -> slot 0 (slot-0 reads ended at s=11;
            // first q3 read at s=24; drained by the s=12 end-of-body sync)
            #pragma unroll
            for (int i = 0; i < 2; ++i) {
                int u = wave + i * 8;
                if (u < 15) {
                    int d = u * 1024 + lane * 16;
                    int sw = d ^ (((d >> 8) & 15) << 4);
                    gload16(xbase + (size_t)3 * ROWB + sw, s_x + d);
                }
            }
        }
        const int tap = s >> 2, ks = s & 3;
        const int kh = tap / 3, kw = tap % 3;
        const int sbase = ((kh + wm) % 3) * XSLOT;
        const int cb = ks * 64 + lg * 16;
        const char* wcur = s_w[s & 1];

        short8 wb[4];
        #pragma unroll
        for (int of = 0; of < 4; ++of)
            wb[of] = *(const short8*)(wcur + (oh * 4 + of) * 1024 + lane * 16);
        short8 xa[2];
        #pragma unroll
        for (int mf = 0; mf < 2; ++mf) {
            int row = mh * 32 + mf * 16 + lr + kw;
            int off = (row * 256 + cb) ^ ((row & 15) << 4);
            xa[mf] = *(const short8*)(s_x + sbase + off);
        }
        #pragma unroll
        for (int mf = 0; mf < 2; ++mf)
            #pragma unroll
            for (int of = 0; of < 4; ++of) {
                if (WHICH == 0)
                    acc[mf][of] = mfma16(xa[mf], wb[of], acc[mf][of]);
                else
                    acc[mf][of] = mfma16(wb[of], xa[mf], acc[mf][of]);
            }
        __syncthreads();             // closes buf reads + drains stage(s+1)
    }

    // 16x16 C/D layout (verified R1/R9): col = lane&15, row = (lane>>4)*4 + r
    if (WHICH == 0) {
        // D[m][o]: m = mh*32 + mf*16 + lg*4 + r, o = oh*64 + of*16 + lr
        __hip_bfloat16* o1 = (__hip_bfloat16*)outp;
        size_t rowb = ((size_t)n * HP + (h0 + wm + 1)) * HP;
        #pragma unroll
        for (int of = 0; of < 4; ++of) {
            int o = oh * 64 + of * 16 + lr;
            float sh = shift[o];
            #pragma unroll
            for (int mf = 0; mf < 2; ++mf) {
                #pragma unroll
                for (int r = 0; r < 4; ++r) {
                    int m = mh * 32 + mf * 16 + lg * 4 + r;
                    if (m < W) {
                        float f = acc[mf][of][r] + sh;
                        f = f > 0.f ? f : 0.f;
                        o1[(rowb + m + 1) * C + o] = __float2bfloat16(f);
                    }
                }
            }
        }
    } else {
        // D[o][m]: o = oh*64 + of*16 + lg*4 + r, m = mh*32 + mf*16 + lr
        float* o2 = (float*)outp;
        int h = h0 + wm;
        #pragma unroll
        for (int mf = 0; mf < 2; ++mf) {
            int m = mh * 32 + mf * 16 + lr;
            if (m < W) {
                #pragma unroll
                for (int of = 0; of < 4; ++of) {
                    int ob = oh * 64 + of * 16 + lg * 4;
                    f32x4 sh = *(const f32x4*)(shift + ob);
                    #pragma unroll
                    for (int r = 0; r < 4; ++r) {
                        int o = ob + r;
                        size_t idx = ((size_t)(n * C + o) * H + h) * W + m;
                        float f = acc[mf][of][r] + sh[r] + ident[idx];
                        o2[idx] = f > 0.f ? f : 0.f;
                    }
                }
            }
        }
    }
}

// ---------------------------------------------------------------------------
extern "C" void kernel_launch(void* const* d_in, const int* in_sizes, int n_in,
                              void* d_out, int out_size, void* d_ws, size_t ws_size,
                              hipStream_t stream)
{
    const float* x  = (const float*)d_in[0];
    const float* w1 = (const float*)d_in[1];
    const float* g1 = (const float*)d_in[2];
    const float* b1 = (const float*)d_in[3];
    const float* m1 = (const float*)d_in[4];
    const float* v1 = (const float*)d_in[5];
    const float* w2 = (const float*)d_in[6];
    const float* g2 = (const float*)d_in[7];
    const float* b2 = (const float*)d_in[8];
    const float* m2 = (const float*)d_in[9];
    const float* v2 = (const float*)d_in[10];
    float* out = (float*)d_out;

    char* ws = (char*)d_ws;
    const size_t PADBUF = (size_t)NN * HP * HP * C * 2;    // 55,107,584 B
    const size_t WBUF   = (size_t)288 * 1024;              // 294,912 B
    size_t oX  = 0;
    size_t oY  = oX + PADBUF + 32768;    // slack for staging over-read
    size_t oW1 = oY + PADBUF + 32768;
    size_t oW2 = oW1 + WBUF;
    size_t oS1 = oW2 + WBUF;
    size_t oS2 = oS1 + 512;

    __hip_bfloat16* Xp  = (__hip_bfloat16*)(ws + oX);
    __hip_bfloat16* Y1  = (__hip_bfloat16*)(ws + oY);
    __hip_bfloat16* W1p = (__hip_bfloat16*)(ws + oW1);
    __hip_bfloat16* W2p = (__hip_bfloat16*)(ws + oW2);
    float* s1 = (float*)(ws + oS1);
    float* s2 = (float*)(ws + oS2);

    zero_halo<<<912, 256, 0, stream>>>(Xp);
    zero_halo<<<912, 256, 0, stream>>>(Y1);

    pack_weights<<<128, 128, 0, stream>>>(w1, g1, b1, m1, v1, W1p, s1);
    pack_weights<<<128, 128, 0, stream>>>(w2, g2, b2, m2, v2, W2p, s2);
    transform_x<<<NN * H, 256, 0, stream>>>(x, Xp);

    conv3x3_kernel<0><<<NN * 28, 512, 0, stream>>>(Xp, W1p, s1, nullptr, (void*)Y1);
    conv3x3_kernel<1><<<NN * 28, 512, 0, stream>>>(Y1, W2p, s2, x, (void*)out);
}

// Round 11
// 238.335 us; speedup vs baseline: 1.5523x; 1.0173x over previous
//
#include <hip/hip_runtime.h>
#include <hip/hip_bf16.h>

typedef __attribute__((ext_vector_type(8))) short short8;
typedef __attribute__((ext_vector_type(4))) float f32x4;

static constexpr int NN = 64;
static constexpr int C  = 128;
static constexpr int H  = 56;
static constexpr int W  = 56;
static constexpr int HP = 58;          // padded spatial extent
static constexpr int ROWB = HP * 256;  // padded row stride in bytes (NHWC bf16)
static constexpr int XSLOT = 15360;    // LDS bytes per X row slot (15 x 1KB)

__device__ __forceinline__ void gload16(const void* g, void* l) {
    __builtin_amdgcn_global_load_lds(
        (const __attribute__((address_space(1))) unsigned int*)g,
        (__attribute__((address_space(3))) unsigned int*)l, 16, 0, 0);
}

__device__ __forceinline__ f32x4 mfma16(short8 a, short8 b, f32x4 c) {
    return __builtin_amdgcn_mfma_f32_16x16x32_bf16(a, b, c, 0, 0, 0);
}

// ---------------------------------------------------------------------------
// Pack weights into 16x16x32 MFMA B-fragment order (verified R9/R10).
// Fragment f = (tap*4 + ks)*8 + ob   (ks = c>>5, ob = o>>4), 1024 B each.
// lane l of frag holds W[o = ob*16 + (l&15)][c = ks*32 + (l>>4)*8 + j] * scale.
// One K-step s = tap*4+ks is a contiguous 8 KB run (8 ob frags) -> LDS tile.
// ---------------------------------------------------------------------------
__global__ __launch_bounds__(128)
void pack_weights(const float* __restrict__ w, const float* __restrict__ g,
                  const float* __restrict__ b, const float* __restrict__ m,
                  const float* __restrict__ v, __hip_bfloat16* __restrict__ Wp,
                  float* __restrict__ shift)
{
    int o = blockIdx.x;
    int c = threadIdx.x;
    float scale = g[o] * rsqrtf(v[o] + 1e-5f);
    if (c == 0) shift[o] = b[o] - m[o] * scale;
    const float* ws = w + ((size_t)o * C + c) * 9;
    int ks = c >> 5, lane = (o & 15) | (((c >> 3) & 3) << 4), jj = c & 7;
    int ob = o >> 4;
    #pragma unroll
    for (int tap = 0; tap < 9; ++tap) {
        size_t f = (size_t)(tap * 4 + ks) * 8 + ob;
        Wp[f * 512 + lane * 8 + jj] = __float2bfloat16(ws[tap] * scale);
    }
}

// ---------------------------------------------------------------------------
// NCHW fp32 -> padded NHWC bf16 (interior only; halo zeroed separately).
// ---------------------------------------------------------------------------
__global__ __launch_bounds__(256)
void transform_x(const float* __restrict__ x, __hip_bfloat16* __restrict__ Xp)
{
    __shared__ float t[C * 57];
    int bid = blockIdx.x;
    int n = bid / H, h = bid % H;
    int tid = threadIdx.x;

    #pragma unroll
    for (int i = 0; i < 7; ++i) {
        int idx4 = i * 256 + tid;
        int c  = idx4 / 14;
        int wq = (idx4 % 14) * 4;
        const float* p = x + ((size_t)(n * C + c)) * (H * W) + h * W + wq;
        float4 vv = *(const float4*)p;
        t[c * 57 + wq + 0] = vv.x;
        t[c * 57 + wq + 1] = vv.y;
        t[c * 57 + wq + 2] = vv.z;
        t[c * 57 + wq + 3] = vv.w;
    }
    __syncthreads();
    #pragma unroll
    for (int i = 0; i < 28; ++i) {
        int idx = i * 256 + tid;
        int c = idx & 127, w = idx >> 7;
        float vv = t[c * 57 + w];
        Xp[(((size_t)n * HP + (h + 1)) * HP + (w + 1)) * C + c] = __float2bfloat16(vv);
    }
}

// ---------------------------------------------------------------------------
// Zero only the halo of a padded NHWC buffer.
// ---------------------------------------------------------------------------
__global__ __launch_bounds__(256)
void zero_halo(__hip_bfloat16* __restrict__ buf)
{
    int idx = blockIdx.x * 256 + threadIdx.x;
    int n = idx / (228 * 16);
    int rem = idx % (228 * 16);
    int p = rem >> 4, l = rem & 15;
    int y, xq;
    if (p < 58)       { y = 0;  xq = p; }
    else if (p < 116) { y = 57; xq = p - 58; }
    else { int q = p - 116; y = 1 + (q >> 1); xq = (q & 1) * 57; }
    short8* dst = (short8*)(buf + (((size_t)n * HP + y) * HP + xq) * C + l * 8);
    *dst = short8{0,0,0,0,0,0,0,0};
}

// ---------------------------------------------------------------------------
// Implicit-GEMM 3x3 conv.  Structure = R10 (passing) with the T4 fix:
// Block = 512 thr (8 waves), 2 output rows x O=128.
// Wave (wm,mh,oh): row h0+wm, m in [mh*32,+32), o in [oh*64,+64),
// acc[2][4] f32x4 = 32 regs.
// X: 3-slot LDS ring, XOR swizzle ((pos&15)<<4) via pre-swizzled gload_lds
//    source; q3 prefetched at body 12, consumed from body 24.
// W: LDS TRIPLE-buffer of 8 KB K-step tiles, 2-body-deep prefetch:
//    body s issues stage(s+2); end-of-body barrier uses COUNTED
//    s_waitcnt vmcnt(1) (vmcnt(0) only at s=34) + raw s_barrier, so each
//    stage has ~2 compute phases (~L2 latency) in flight — never drain0.
//    Invariants: buf[(s+2)%3] last read at body s-1 (barrier-ordered before
//    the write); stage(s) completion forced by vmcnt(1) at end of body s-1.
// T5: setprio(1) around the MFMA cluster (phase-split schedule).
// WHICH==0: D[m][o] -> relu(D+shift) -> NHWC bf16 padded (Y1)
// WHICH==1: D[o][m] -> relu(D+shift+identity) -> NCHW fp32
// ---------------------------------------------------------------------------
template<int WHICH>
__global__ __launch_bounds__(512, 2)
void conv3x3_kernel(const __hip_bfloat16* __restrict__ Xp,
                    const __hip_bfloat16* __restrict__ Wp,
                    const float* __restrict__ shift,
                    const float* __restrict__ ident,
                    void* __restrict__ outp)
{
    __shared__ char s_x[3 * XSLOT + 2048];   // 46 KB ring + read-overhang pad
    __shared__ char s_w[3][8192];            // W triple buffer (one K-step each)

    const int tid  = threadIdx.x;
    const int wave = tid >> 6;       // 0..7
    const int lane = tid & 63;
    const int lr   = lane & 15;
    const int lg   = lane >> 4;      // 0..3
    const int wm   = wave >> 2;      // output row (0..1)
    const int mh   = (wave >> 1) & 1;// m-half (0..1)
    const int oh   = wave & 1;       // o-half (0..1)

    const int bid0 = blockIdx.x;
    const int bid  = (bid0 & 7) * 224 + (bid0 >> 3);   // XCD swizzle (1792=8*224)
    const int n = bid / 28, h0 = (bid % 28) * 2;

    const char* xbase = (const char*)Xp + ((size_t)n * HP + h0) * ROWB;
    const char* wbase = (const char*)Wp;

    // prologue: stage padded rows q0..q2 -> slots 0..2 (45 x 1KB units)
    #pragma unroll
    for (int i = 0; i < 6; ++i) {
        int u = wave + i * 8;
        if (u < 45) {
            int q = u / 15, blk = u % 15;
            int d = blk * 1024 + lane * 16;
            int s = d ^ (((d >> 8) & 15) << 4);
            gload16(xbase + (size_t)q * ROWB + s, s_x + q * XSLOT + d);
        }
    }
    // stage W K-steps 0,1 -> s_w[0], s_w[1]
    gload16(wbase + tid * 16, s_w[0] + tid * 16);
    gload16(wbase + 8192 + tid * 16, s_w[1] + tid * 16);

    f32x4 acc[2][4];
    #pragma unroll
    for (int i = 0; i < 2; ++i)
        #pragma unroll
        for (int j = 0; j < 4; ++j)
            acc[i][j] = f32x4{0.f, 0.f, 0.f, 0.f};

    __syncthreads();                 // full drain: X q0..q2 + W steps 0,1

    #pragma unroll
    for (int s = 0; s < 36; ++s) {
        // 2-deep W prefetch: issue stage(s+2) into buf[(s+2)%3]
        if (s < 34)
            gload16(wbase + (size_t)(s + 2) * 8192 + tid * 16,
                    s_w[(s + 2) % 3] + tid * 16);
        if (s == 12) {
            // prefetch padded row q3 -> slot 0 (slot-0 reads ended at s=11;
            // first q3 read at s=24; forced complete by later counted waits)
            #pragma unroll
            for (int i = 0; i < 2; ++i) {
                int u = wave + i * 8;
                if (u < 15) {
                    int d = u * 1024 + lane * 16;
                    int sw = d ^ (((d >> 8) & 15) << 4);
                    gload16(xbase + (size_t)3 * ROWB + sw, s_x + d);
                }
            }
        }
        const int tap = s >> 2, ks = s & 3;
        const int kh = tap / 3, kw = tap % 3;
        const int sbase = ((kh + wm) % 3) * XSLOT;
        const int cb = ks * 64 + lg * 16;
        const char* wcur = s_w[s % 3];

        short8 wb[4];
        #pragma unroll
        for (int of = 0; of < 4; ++of)
            wb[of] = *(const short8*)(wcur + (oh * 4 + of) * 1024 + lane * 16);
        short8 xa[2];
        #pragma unroll
        for (int mf = 0; mf < 2; ++mf) {
            int row = mh * 32 + mf * 16 + lr + kw;
            int off = (row * 256 + cb) ^ ((row & 15) << 4);
            xa[mf] = *(const short8*)(s_x + sbase + off);
        }
        __builtin_amdgcn_s_setprio(1);
        #pragma unroll
        for (int mf = 0; mf < 2; ++mf)
            #pragma unroll
            for (int of = 0; of < 4; ++of) {
                if (WHICH == 0)
                    acc[mf][of] = mfma16(xa[mf], wb[of], acc[mf][of]);
                else
                    acc[mf][of] = mfma16(wb[of], xa[mf], acc[mf][of]);
            }
        __builtin_amdgcn_s_setprio(0);

        if (s < 35) {
            __builtin_amdgcn_sched_barrier(0);
            if (s == 34)
                asm volatile("s_waitcnt vmcnt(0)" ::: "memory");
            else
                asm volatile("s_waitcnt vmcnt(1)" ::: "memory");
            __builtin_amdgcn_s_barrier();
            __builtin_amdgcn_sched_barrier(0);
        }
    }

    // 16x16 C/D layout (verified R1/R9/R10): col = lane&15, row = (lane>>4)*4+r
    if (WHICH == 0) {
        // D[m][o]: m = mh*32 + mf*16 + lg*4 + r, o = oh*64 + of*16 + lr
        __hip_bfloat16* o1 = (__hip_bfloat16*)outp;
        size_t rowb = ((size_t)n * HP + (h0 + wm + 1)) * HP;
        #pragma unroll
        for (int of = 0; of < 4; ++of) {
            int o = oh * 64 + of * 16 + lr;
            float sh = shift[o];
            #pragma unroll
            for (int mf = 0; mf < 2; ++mf) {
                #pragma unroll
                for (int r = 0; r < 4; ++r) {
                    int m = mh * 32 + mf * 16 + lg * 4 + r;
                    if (m < W) {
                        float f = acc[mf][of][r] + sh;
                        f = f > 0.f ? f : 0.f;
                        o1[(rowb + m + 1) * C + o] = __float2bfloat16(f);
                    }
                }
            }
        }
    } else {
        // D[o][m]: o = oh*64 + of*16 + lg*4 + r, m = mh*32 + mf*16 + lr
        float* o2 = (float*)outp;
        int h = h0 + wm;
        #pragma unroll
        for (int mf = 0; mf < 2; ++mf) {
            int m = mh * 32 + mf * 16 + lr;
            if (m < W) {
                #pragma unroll
                for (int of = 0; of < 4; ++of) {
                    int ob = oh * 64 + of * 16 + lg * 4;
                    f32x4 sh = *(const f32x4*)(shift + ob);
                    #pragma unroll
                    for (int r = 0; r < 4; ++r) {
                        int o = ob + r;
                        size_t idx = ((size_t)(n * C + o) * H + h) * W + m;
                        float f = acc[mf][of][r] + sh[r] + ident[idx];
                        o2[idx] = f > 0.f ? f : 0.f;
                    }
                }
            }
        }
    }
}

// ---------------------------------------------------------------------------
extern "C" void kernel_launch(void* const* d_in, const int* in_sizes, int n_in,
                              void* d_out, int out_size, void* d_ws, size_t ws_size,
                              hipStream_t stream)
{
    const float* x  = (const float*)d_in[0];
    const float* w1 = (const float*)d_in[1];
    const float* g1 = (const float*)d_in[2];
    const float* b1 = (const float*)d_in[3];
    const float* m1 = (const float*)d_in[4];
    const float* v1 = (const float*)d_in[5];
    const float* w2 = (const float*)d_in[6];
    const float* g2 = (const float*)d_in[7];
    const float* b2 = (const float*)d_in[8];
    const float* m2 = (const float*)d_in[9];
    const float* v2 = (const float*)d_in[10];
    float* out = (float*)d_out;

    char* ws = (char*)d_ws;
    const size_t PADBUF = (size_t)NN * HP * HP * C * 2;    // 55,107,584 B
    const size_t WBUF   = (size_t)288 * 1024;              // 294,912 B
    size_t oX  = 0;
    size_t oY  = oX + PADBUF + 32768;    // slack for staging over-read
    size_t oW1 = oY + PADBUF + 32768;
    size_t oW2 = oW1 + WBUF;
    size_t oS1 = oW2 + WBUF;
    size_t oS2 = oS1 + 512;

    __hip_bfloat16* Xp  = (__hip_bfloat16*)(ws + oX);
    __hip_bfloat16* Y1  = (__hip_bfloat16*)(ws + oY);
    __hip_bfloat16* W1p = (__hip_bfloat16*)(ws + oW1);
    __hip_bfloat16* W2p = (__hip_bfloat16*)(ws + oW2);
    float* s1 = (float*)(ws + oS1);
    float* s2 = (float*)(ws + oS2);

    zero_halo<<<912, 256, 0, stream>>>(Xp);
    zero_halo<<<912, 256, 0, stream>>>(Y1);

    pack_weights<<<128, 128, 0, stream>>>(w1, g1, b1, m1, v1, W1p, s1);
    pack_weights<<<128, 128, 0, stream>>>(w2, g2, b2, m2, v2, W2p, s2);
    transform_x<<<NN * H, 256, 0, stream>>>(x, Xp);

    conv3x3_kernel<0><<<NN * 28, 512, 0, stream>>>(Xp, W1p, s1, nullptr, (void*)Y1);
    conv3x3_kernel<1><<<NN * 28, 512, 0, stream>>>(Y1, W2p, s2, x, (void*)out);
}